// Round 9
// baseline (1154.793 us; speedup 1.0000x reference)
//
#include <hip/hip_runtime.h>

#define N_NODES 100000
#define N_EDGES 1600000
#define IN_DIM  192
#define H1      64
#define H2      32
#define NBKT    391          // ceil(N_NODES/256) buckets (both dst- and src-keyed)
#define CAP_D   4608         // bucket capacity (mean 4096, sigma 64 -> 8 sigma)
#define K1GRID  2345         // b%3==0 -> pass1 (782), else gemm1 (1563)

typedef __attribute__((ext_vector_type(8))) short short8;
typedef __attribute__((ext_vector_type(4))) float f32x4;

__device__ inline short f2bf(float f) {
    union { float f; unsigned u; } v; v.f = f;
    unsigned r = (v.u + 0x7FFFu + ((v.u >> 16) & 1u)) >> 16;
    return (short)r;
}
__device__ inline float bf2f(unsigned short s) {
    union { unsigned u; float f; } v; v.u = ((unsigned)s) << 16;
    return v.f;
}

// ---------------- init: bucket cursors (dst at [0..511], src at [512..1023]) ----------------
__global__ __launch_bounds__(1024) void init_kernel(int* __restrict__ bucket_next) {
    int i = threadIdx.x;
    bucket_next[i] = (i & 511) * CAP_D;
}

// ---------------- weight prep: Bt1[128][192], Bt2[64][64], bf16, N-major ----------------
__global__ __launch_bounds__(256) void prep_w_kernel(
    const float* __restrict__ W0_1, const float* __restrict__ W1_1,
    const float* __restrict__ W0_2, const float* __restrict__ W1_2,
    short* __restrict__ Bt1, short* __restrict__ Bt2) {
    int idx = blockIdx.x * 256 + threadIdx.x;
    if (idx < 128 * IN_DIM) {
        int n = idx / IN_DIM, k = idx % IN_DIM;
        float v = (n < H1) ? W0_1[(size_t)k * H1 + n] : W1_1[(size_t)k * H1 + (n - H1)];
        Bt1[idx] = f2bf(v);
    } else {
        int j = idx - 128 * IN_DIM;
        if (j < 64 * H1) {
            int n = j / H1, k = j % H1;
            float v = (n < H2) ? W0_2[(size_t)k * H2 + n] : W1_2[(size_t)k * H2 + (n - H2)];
            Bt2[j] = f2bf(v);
        }
    }
}

// ---- K1 fused: pass1 dual binning (dst 4B payload, src 1B count-token) || gemm1 MFMA ----
__global__ __launch_bounds__(256) void k1_fused(
    const int* __restrict__ edges, int* __restrict__ bucket_next,
    int* __restrict__ bins_dst, unsigned char* __restrict__ bins_src,
    const float* __restrict__ verts, const short* __restrict__ Bt1,
    const float* __restrict__ b1, short* __restrict__ hbase, short* __restrict__ y1b) {
    __shared__ int cntd[512];
    __shared__ int curd[512];
    __shared__ int cnts[512];
    __shared__ int curs[512];
    int b = blockIdx.x;
    int tid = threadIdx.x;
    if (b % 3 == 0) {
        // ---------------- pass1 role ----------------
        int p = b / 3;                       // 0..781
        cntd[tid] = 0; cntd[tid + 256] = 0;
        cnts[tid] = 0; cnts[tid + 256] = 0;
        __syncthreads();
        int ebase = p * 2048 + tid * 8;
        int2 ed[8]; int bd[8], bs[8];
#pragma unroll
        for (int i = 0; i < 8; ++i) {
            int e = ebase + i;
            if (e < N_EDGES) {
                ed[i] = ((const int2*)edges)[e];
                bd[i] = ed[i].y >> 8;
                bs[i] = ed[i].x >> 8;
                atomicAdd(&cntd[bd[i]], 1);
                atomicAdd(&cnts[bs[i]], 1);
            } else { bd[i] = -1; bs[i] = -1; }
        }
        __syncthreads();
        {
            int c;
            c = cntd[tid];       curd[tid]       = (c > 0) ? atomicAdd(&bucket_next[tid], c) : 0;
            c = cntd[tid + 256]; curd[tid + 256] = (c > 0) ? atomicAdd(&bucket_next[tid + 256], c) : 0;
            c = cnts[tid];       curs[tid]       = (c > 0) ? atomicAdd(&bucket_next[512 + tid], c) : 0;
            c = cnts[tid + 256]; curs[tid + 256] = (c > 0) ? atomicAdd(&bucket_next[512 + tid + 256], c) : 0;
        }
        __syncthreads();
#pragma unroll
        for (int i = 0; i < 8; ++i) {
            if (bd[i] >= 0) {
                int sd = atomicAdd(&curd[bd[i]], 1);
                if (sd < (bd[i] + 1) * CAP_D)
                    bins_dst[sd] = ((ed[i].y & 255) << 17) | ed[i].x;
                int ss = atomicAdd(&curs[bs[i]], 1);
                if (ss < (bs[i] + 1) * CAP_D)
                    bins_src[ss] = (unsigned char)(ed[i].x & 255);
            }
        }
        return;
    }
    // ---------------- gemm1 role: 16 rows/wave, N=128 (8 col-frags), K=192 ----------------
    int g = b - b / 3 - 1;                   // 0..1562
    int lane = tid & 63;
    int wave = tid >> 6;
    int rowbase = g * 64 + wave * 16;
    int lr = lane & 15;
    int lk = (lane >> 4) * 8;

    int row = rowbase + lr;
    int rc = (row < N_NODES) ? row : (N_NODES - 1);
    const float* p = verts + (size_t)rc * IN_DIM + lk;
    short8 a[6];
#pragma unroll
    for (int ks = 0; ks < 6; ++ks) {
        f32x4 u0 = *(const f32x4*)(p + ks * 32);
        f32x4 u1 = *(const f32x4*)(p + ks * 32 + 4);
        short8 t;
        t[0] = f2bf(u0[0]); t[1] = f2bf(u0[1]); t[2] = f2bf(u0[2]); t[3] = f2bf(u0[3]);
        t[4] = f2bf(u1[0]); t[5] = f2bf(u1[1]); t[6] = f2bf(u1[2]); t[7] = f2bf(u1[3]);
        a[ks] = t;
    }

    f32x4 acc[8] = {};
#pragma unroll
    for (int cf = 0; cf < 8; ++cf) {
        const short* bp = Bt1 + (size_t)(cf * 16 + lr) * IN_DIM + lk;
#pragma unroll
        for (int ks = 0; ks < 6; ++ks) {
            short8 bb = *(const short8*)(bp + ks * 32);
            acc[cf] = __builtin_amdgcn_mfma_f32_16x16x32_bf16(a[ks], bb, acc[cf], 0, 0, 0);
        }
    }

    int srow = (lane >> 4) * 4;
#pragma unroll
    for (int cf = 0; cf < 8; ++cf) {
        int colc = cf * 16 + lr;
        float bias = (colc < H1) ? b1[colc] : 0.f;
#pragma unroll
        for (int r = 0; r < 4; ++r) {
            int orow = rowbase + srow + r;
            if (orow < N_NODES) {
                float v = acc[cf][r];
                if (colc < H1) hbase[(size_t)orow * H1 + colc] = f2bf(v + bias);
                else           y1b[(size_t)orow * H1 + (colc - H1)] = f2bf(v);
            }
        }
    }
}

// ---- dinv: per-bucket LDS histogram of bins_src -> dinv ----
__global__ __launch_bounds__(256) void dinv_kernel(
    const unsigned char* __restrict__ bins_src, const int* __restrict__ bucket_next,
    float* __restrict__ dinv) {
    __shared__ int dcnt[256];
    int b = blockIdx.x;                  // 0..390
    int tid = threadIdx.x;
    int beg = b * CAP_D;
    int fills = bucket_next[512 + b] - beg;
    if (fills > CAP_D) fills = CAP_D;
    dcnt[tid] = 0;
    __syncthreads();
    for (int i = tid; i < fills; i += 256)
        atomicAdd(&dcnt[bins_src[beg + i]], 1);
    __syncthreads();
    int n = b * 256 + tid;
    if (n < N_NODES) {
        int d = dcnt[tid];
        dinv[n] = (d > 0) ? rsqrtf((float)d) : 0.f;
    }
}

// ---- gather1 stream: one block per half-bucket, LDS fp32 accumulate over the edge stream ----
// acc[128][64] fp32 = 32 KB. Epilogue fuses hbase + relu + bf16 cast.
__global__ __launch_bounds__(256) void gather1_kernel(
    const int* __restrict__ bins_dst, const int* __restrict__ bucket_next,
    const float* __restrict__ dinv, const unsigned short* __restrict__ hbase,
    const unsigned short* __restrict__ y1b, short* __restrict__ hb) {
    __shared__ float acc[128 * H1];
    int blk = blockIdx.x;
    int bkt = blk >> 1, half = blk & 1;
    int tid = threadIdx.x, lane = tid & 63, wv = tid >> 6;
    int beg = bkt * CAP_D;
    int fill = bucket_next[bkt] - beg;
    if (fill > CAP_D) fill = CAP_D;
    for (int i = tid; i < 128 * H1 / 4; i += 256)
        ((f32x4*)acc)[i] = (f32x4){0.f, 0.f, 0.f, 0.f};
    __syncthreads();
    int i = wv;
    for (; i + 28 < fill; i += 32) {
        int pay[8];
#pragma unroll
        for (int j = 0; j < 8; ++j) pay[j] = bins_dst[beg + i + 4 * j];
#pragma unroll
        for (int j = 0; j < 8; ++j) {
            int dl = pay[j] >> 17;
            if ((dl >> 7) == half) {               // wave-uniform branch
                int src = pay[j] & 0x1FFFF;
                float w = dinv[src];
                float v = bf2f(y1b[(size_t)src * H1 + lane]);
                atomicAdd(&acc[(dl & 127) * H1 + lane], w * v);
            }
        }
    }
    for (; i < fill; i += 4) {
        int pay0 = bins_dst[beg + i];
        int dl = pay0 >> 17;
        if ((dl >> 7) == half) {
            int src = pay0 & 0x1FFFF;
            atomicAdd(&acc[(dl & 127) * H1 + lane], dinv[src] * bf2f(y1b[(size_t)src * H1 + lane]));
        }
    }
    __syncthreads();
    int nbase = bkt * 256 + half * 128;
    for (int r = wv; r < 128; r += 4) {
        int n = nbase + r;
        if (n < N_NODES) {
            float hf = bf2f(hbase[(size_t)n * H1 + lane]) - dinv[n] * acc[r * H1 + lane];
            hb[(size_t)n * H1 + lane] = f2bf(fmaxf(hf, 0.f));
        }
    }
}

// ---------------- layer-2 MFMA GEMM: [out | y2b] = relu(h) @ [W0_2 | W1_2] ----------------
__global__ __launch_bounds__(256) void gemm2_mfma(
    const short* __restrict__ hb, const short* __restrict__ Bt2,
    const float* __restrict__ b2, float* __restrict__ out, short* __restrict__ y2b) {
    int lane = threadIdx.x & 63;
    int wave = threadIdx.x >> 6;
    int rowbase = blockIdx.x * 128 + wave * 32;
    int lr = lane & 15;
    int lk = (lane >> 4) * 8;

    short8 a[2][2];
#pragma unroll
    for (int mr = 0; mr < 2; ++mr) {
        int row = rowbase + mr * 16 + lr;
        int rc = (row < N_NODES) ? row : (N_NODES - 1);
        const short* p = hb + (size_t)rc * H1 + lk;
        a[mr][0] = *(const short8*)(p);
        a[mr][1] = *(const short8*)(p + 32);
    }

    f32x4 acc[2][4] = {};
#pragma unroll
    for (int cf = 0; cf < 4; ++cf) {
        const short* bp = Bt2 + (size_t)(cf * 16 + lr) * H1 + lk;
#pragma unroll
        for (int ks = 0; ks < 2; ++ks) {
            short8 b = *(const short8*)(bp + ks * 32);
            acc[0][cf] = __builtin_amdgcn_mfma_f32_16x16x32_bf16(a[0][ks], b, acc[0][cf], 0, 0, 0);
            acc[1][cf] = __builtin_amdgcn_mfma_f32_16x16x32_bf16(a[1][ks], b, acc[1][cf], 0, 0, 0);
        }
    }

    int srow = (lane >> 4) * 4;
#pragma unroll
    for (int mr = 0; mr < 2; ++mr) {
#pragma unroll
        for (int cf = 0; cf < 4; ++cf) {
            int colc = cf * 16 + lr;
            float bias = (colc < H2) ? b2[colc] : 0.f;
#pragma unroll
            for (int r = 0; r < 4; ++r) {
                int row = rowbase + mr * 16 + srow + r;
                if (row < N_NODES) {
                    float v = acc[mr][cf][r];
                    if (colc < H2) out[(size_t)row * H2 + colc] = v + bias;
                    else           y2b[(size_t)row * H2 + (colc - H2)] = f2bf(v);
                }
            }
        }
    }
}

// ---- gather2 stream: acc[128][32] fp32 = 16 KB, 2 edges/wave; epilogue out -= dinv*acc ----
__global__ __launch_bounds__(256) void gather2_kernel(
    const int* __restrict__ bins_dst, const int* __restrict__ bucket_next,
    const float* __restrict__ dinv, const unsigned short* __restrict__ y2b,
    float* __restrict__ out) {
    __shared__ float acc[128 * H2];
    int blk = blockIdx.x;
    int bkt = blk >> 1, half = blk & 1;
    int tid = threadIdx.x, lane = tid & 63, wv = tid >> 6;
    int sub = lane >> 5, c = lane & 31;
    int beg = bkt * CAP_D;
    int fill = bucket_next[bkt] - beg;
    if (fill > CAP_D) fill = CAP_D;
    for (int i = tid; i < 128 * H2 / 4; i += 256)
        ((f32x4*)acc)[i] = (f32x4){0.f, 0.f, 0.f, 0.f};
    __syncthreads();
    int i = wv * 2 + sub;
    for (; i + 24 < fill; i += 32) {
        int pay[4];
#pragma unroll
        for (int j = 0; j < 4; ++j) pay[j] = bins_dst[beg + i + 8 * j];
#pragma unroll
        for (int j = 0; j < 4; ++j) {
            int dl = pay[j] >> 17;
            if ((dl >> 7) == half) {               // uniform within the 32-lane half
                int src = pay[j] & 0x1FFFF;
                atomicAdd(&acc[(dl & 127) * H2 + c], dinv[src] * bf2f(y2b[(size_t)src * H2 + c]));
            }
        }
    }
    for (; i < fill; i += 8) {
        int pay0 = bins_dst[beg + i];
        int dl = pay0 >> 17;
        if ((dl >> 7) == half) {
            int src = pay0 & 0x1FFFF;
            atomicAdd(&acc[(dl & 127) * H2 + c], dinv[src] * bf2f(y2b[(size_t)src * H2 + c]));
        }
    }
    __syncthreads();
    int nbase = bkt * 256 + half * 128;
    for (int idx = tid; idx < 128 * H2; idx += 256) {
        int r = idx >> 5, cc = idx & 31;
        int n = nbase + r;
        if (n < N_NODES)
            out[(size_t)n * H2 + cc] -= dinv[n] * acc[idx];
    }
}

extern "C" void kernel_launch(void* const* d_in, const int* in_sizes, int n_in,
                              void* d_out, int out_size, void* d_ws, size_t ws_size,
                              hipStream_t stream) {
    const float* verts = (const float*)d_in[0];
    const int*   edges = (const int*)  d_in[1];
    const float* W0_1  = (const float*)d_in[2];
    const float* W1_1  = (const float*)d_in[3];
    const float* b1    = (const float*)d_in[4];
    const float* W0_2  = (const float*)d_in[5];
    const float* W1_2  = (const float*)d_in[6];
    const float* b2    = (const float*)d_in[7];
    float* out = (float*)d_out;

    char* ws = (char*)d_ws;
    auto align256 = [](size_t x) { return (x + 255) & ~(size_t)255; };
    size_t o = 0;
    auto alloc = [&](size_t bytes) { size_t r = o; o = align256(o + bytes); return r; };

    int*   bucket_next = (int*)  (ws + alloc((size_t)1024 * 4));
    int*   bins_dst    = (int*)  (ws + alloc((size_t)NBKT * CAP_D * 4));
    unsigned char* bins_src = (unsigned char*)(ws + alloc((size_t)NBKT * CAP_D));
    float* dinv        = (float*)(ws + alloc((size_t)N_NODES * 4));
    short* Bt1         = (short*)(ws + alloc((size_t)128 * IN_DIM * 2));
    short* Bt2         = (short*)(ws + alloc((size_t)64 * H1 * 2));
    short* hbase       = (short*)(ws + alloc((size_t)N_NODES * H1 * 2));
    short* y1b         = (short*)(ws + alloc((size_t)N_NODES * H1 * 2));
    short* hb          = (short*)(ws + alloc((size_t)N_NODES * H1 * 2));
    short* y2b         = (short*)(ws + alloc((size_t)N_NODES * H2 * 2));

    init_kernel  <<<1, 1024, 0, stream>>>(bucket_next);
    prep_w_kernel<<<(128 * IN_DIM + 64 * H1 + 255) / 256, 256, 0, stream>>>(W0_1, W1_1, W0_2, W1_2, Bt1, Bt2);

    k1_fused   <<<K1GRID, 256, 0, stream>>>(edges, bucket_next, bins_dst, bins_src,
                                            verts, Bt1, b1, hbase, y1b);
    dinv_kernel<<<NBKT, 256, 0, stream>>>(bins_src, bucket_next, dinv);

    gather1_kernel<<<NBKT * 2, 256, 0, stream>>>(bins_dst, bucket_next, dinv,
                                                 (const unsigned short*)hbase,
                                                 (const unsigned short*)y1b, hb);
    gemm2_mfma    <<<(N_NODES + 127) / 128, 256, 0, stream>>>(hb, Bt2, b2, out, y2b);
    gather2_kernel<<<NBKT * 2, 256, 0, stream>>>(bins_dst, bucket_next, dinv,
                                                 (const unsigned short*)y2b, out);
}

// Round 10
// 206.448 us; speedup vs baseline: 5.5936x; 5.5936x over previous
//
#include <hip/hip_runtime.h>

#define N_NODES 100000
#define N_EDGES 1600000
#define IN_DIM  192
#define H1      64
#define H2      32
#define NBKT    391          // ceil(N_NODES/256) buckets (both dst- and src-keyed)
#define CAP_D   4608         // bucket capacity (mean 4096, sigma 64 -> 8 sigma)
#define K1GRID  2345         // b%3==0 -> pass1 (782), else gemm1 (1563)

typedef __attribute__((ext_vector_type(8))) short short8;
typedef __attribute__((ext_vector_type(4))) float f32x4;

__device__ inline short f2bf(float f) {
    union { float f; unsigned u; } v; v.f = f;
    unsigned r = (v.u + 0x7FFFu + ((v.u >> 16) & 1u)) >> 16;
    return (short)r;
}
__device__ inline float bf2f(unsigned short s) {
    union { unsigned u; float f; } v; v.u = ((unsigned)s) << 16;
    return v.f;
}

// ---------------- init: bucket cursors (dst at [0..511], src at [512..1023]) ----------------
__global__ __launch_bounds__(1024) void init_kernel(int* __restrict__ bucket_next) {
    int i = threadIdx.x;
    bucket_next[i] = (i & 511) * CAP_D;
}

// ---------------- weight prep: Bt1[128][192], Bt2[64][64], bf16, N-major ----------------
__global__ __launch_bounds__(256) void prep_w_kernel(
    const float* __restrict__ W0_1, const float* __restrict__ W1_1,
    const float* __restrict__ W0_2, const float* __restrict__ W1_2,
    short* __restrict__ Bt1, short* __restrict__ Bt2) {
    int idx = blockIdx.x * 256 + threadIdx.x;
    if (idx < 128 * IN_DIM) {
        int n = idx / IN_DIM, k = idx % IN_DIM;
        float v = (n < H1) ? W0_1[(size_t)k * H1 + n] : W1_1[(size_t)k * H1 + (n - H1)];
        Bt1[idx] = f2bf(v);
    } else {
        int j = idx - 128 * IN_DIM;
        if (j < 64 * H1) {
            int n = j / H1, k = j % H1;
            float v = (n < H2) ? W0_2[(size_t)k * H2 + n] : W1_2[(size_t)k * H2 + (n - H2)];
            Bt2[j] = f2bf(v);
        }
    }
}

// ---- K1 fused: pass1 dual binning (dst 4B payload, src 1B count-token) || gemm1 MFMA ----
__global__ __launch_bounds__(256) void k1_fused(
    const int* __restrict__ edges, int* __restrict__ bucket_next,
    int* __restrict__ bins_dst, unsigned char* __restrict__ bins_src,
    const float* __restrict__ verts, const short* __restrict__ Bt1,
    const float* __restrict__ b1, short* __restrict__ hbase, short* __restrict__ y1b) {
    __shared__ int cntd[512];
    __shared__ int curd[512];
    __shared__ int cnts[512];
    __shared__ int curs[512];
    int b = blockIdx.x;
    int tid = threadIdx.x;
    if (b % 3 == 0) {
        // ---------------- pass1 role ----------------
        int p = b / 3;                       // 0..781
        cntd[tid] = 0; cntd[tid + 256] = 0;
        cnts[tid] = 0; cnts[tid + 256] = 0;
        __syncthreads();
        int ebase = p * 2048 + tid * 8;
        int2 ed[8]; int bd[8], bs[8];
#pragma unroll
        for (int i = 0; i < 8; ++i) {
            int e = ebase + i;
            if (e < N_EDGES) {
                ed[i] = ((const int2*)edges)[e];
                bd[i] = ed[i].y >> 8;
                bs[i] = ed[i].x >> 8;
                atomicAdd(&cntd[bd[i]], 1);
                atomicAdd(&cnts[bs[i]], 1);
            } else { bd[i] = -1; bs[i] = -1; }
        }
        __syncthreads();
        {
            int c;
            c = cntd[tid];       curd[tid]       = (c > 0) ? atomicAdd(&bucket_next[tid], c) : 0;
            c = cntd[tid + 256]; curd[tid + 256] = (c > 0) ? atomicAdd(&bucket_next[tid + 256], c) : 0;
            c = cnts[tid];       curs[tid]       = (c > 0) ? atomicAdd(&bucket_next[512 + tid], c) : 0;
            c = cnts[tid + 256]; curs[tid + 256] = (c > 0) ? atomicAdd(&bucket_next[512 + tid + 256], c) : 0;
        }
        __syncthreads();
#pragma unroll
        for (int i = 0; i < 8; ++i) {
            if (bd[i] >= 0) {
                int sd = atomicAdd(&curd[bd[i]], 1);
                if (sd < (bd[i] + 1) * CAP_D)
                    bins_dst[sd] = ((ed[i].y & 255) << 17) | ed[i].x;
                int ss = atomicAdd(&curs[bs[i]], 1);
                if (ss < (bs[i] + 1) * CAP_D)
                    bins_src[ss] = (unsigned char)(ed[i].x & 255);
            }
        }
        return;
    }
    // ---------------- gemm1 role: 16 rows/wave, N=128 (8 col-frags), K=192 ----------------
    int g = b - b / 3 - 1;                   // 0..1562
    int lane = tid & 63;
    int wave = tid >> 6;
    int rowbase = g * 64 + wave * 16;
    int lr = lane & 15;
    int lk = (lane >> 4) * 8;

    int row = rowbase + lr;
    int rc = (row < N_NODES) ? row : (N_NODES - 1);
    const float* p = verts + (size_t)rc * IN_DIM + lk;
    short8 a[6];
#pragma unroll
    for (int ks = 0; ks < 6; ++ks) {
        f32x4 u0 = *(const f32x4*)(p + ks * 32);
        f32x4 u1 = *(const f32x4*)(p + ks * 32 + 4);
        short8 t;
        t[0] = f2bf(u0[0]); t[1] = f2bf(u0[1]); t[2] = f2bf(u0[2]); t[3] = f2bf(u0[3]);
        t[4] = f2bf(u1[0]); t[5] = f2bf(u1[1]); t[6] = f2bf(u1[2]); t[7] = f2bf(u1[3]);
        a[ks] = t;
    }

    f32x4 acc[8] = {};
#pragma unroll
    for (int cf = 0; cf < 8; ++cf) {
        const short* bp = Bt1 + (size_t)(cf * 16 + lr) * IN_DIM + lk;
#pragma unroll
        for (int ks = 0; ks < 6; ++ks) {
            short8 bb = *(const short8*)(bp + ks * 32);
            acc[cf] = __builtin_amdgcn_mfma_f32_16x16x32_bf16(a[ks], bb, acc[cf], 0, 0, 0);
        }
    }

    int srow = (lane >> 4) * 4;
#pragma unroll
    for (int cf = 0; cf < 8; ++cf) {
        int colc = cf * 16 + lr;
        float bias = (colc < H1) ? b1[colc] : 0.f;
#pragma unroll
        for (int r = 0; r < 4; ++r) {
            int orow = rowbase + srow + r;
            if (orow < N_NODES) {
                float v = acc[cf][r];
                if (colc < H1) hbase[(size_t)orow * H1 + colc] = f2bf(v + bias);
                else           y1b[(size_t)orow * H1 + (colc - H1)] = f2bf(v);
            }
        }
    }
}

// ---- pass2: per-bucket CSR build + deg histogram -> dinv + y1s = dinv*y1b prescale ----
__global__ __launch_bounds__(256) void csr_kernel(
    const int* __restrict__ bins_dst, const unsigned char* __restrict__ bins_src,
    const int* __restrict__ bucket_next, float* __restrict__ dinv,
    int* __restrict__ row_beg, int* __restrict__ row_end, int* __restrict__ col,
    const unsigned short* __restrict__ y1b, short* __restrict__ y1s) {
    __shared__ int cnt_l[256];
    __shared__ int seg_l[256];
    __shared__ int s[256];
    __shared__ int dcnt[256];
    __shared__ float dinv_l[256];
    int b = blockIdx.x;                  // 0..390
    int tid = threadIdx.x;
    int beg = b * CAP_D;
    int filld = bucket_next[b] - beg;
    if (filld > CAP_D) filld = CAP_D;
    int fills = bucket_next[512 + b] - beg;
    if (fills > CAP_D) fills = CAP_D;
    cnt_l[tid] = 0;
    dcnt[tid] = 0;
    __syncthreads();
    for (int i = tid; i < filld; i += 256)
        atomicAdd(&cnt_l[bins_dst[beg + i] >> 17], 1);
    for (int i = tid; i < fills; i += 256)
        atomicAdd(&dcnt[bins_src[beg + i]], 1);
    __syncthreads();
    int v = cnt_l[tid];
    s[tid] = v;
    __syncthreads();
    for (int off = 1; off < 256; off <<= 1) {
        int t = (tid >= off) ? s[tid - off] : 0;
        __syncthreads();
        s[tid] += t;
        __syncthreads();
    }
    int excl = s[tid] - v;
    seg_l[tid] = beg + excl;             // global cursor for placement
    int n = b * 256 + tid;
    int d = dcnt[tid];
    float dv = (d > 0) ? rsqrtf((float)d) : 0.f;
    dinv_l[tid] = dv;
    if (n < N_NODES) {
        row_beg[n] = beg + excl;
        row_end[n] = beg + excl + v;
        dinv[n] = dv;
    }
    __syncthreads();
    for (int i = tid; i < filld; i += 256) {
        int w = bins_dst[beg + i];
        int slot = atomicAdd(&seg_l[w >> 17], 1);   // LDS returning
        col[slot] = w & 0x1FFFF;
    }
    // y1s = dinv[row] * y1b[row], linear over this block's 256 rows
    int nb = b * 256;
    int nmax = N_NODES - nb; if (nmax > 256) nmax = 256;
    for (int idx = tid; idx < nmax * 8; idx += 256) {
        int r = idx >> 3, j = idx & 7;
        float w = dinv_l[r];
        size_t off = (size_t)(nb + r) * H1 + j * 8;
        short8 vv = *(const short8*)&y1b[off];
        short8 o;
#pragma unroll
        for (int q = 0; q < 8; ++q) o[q] = f2bf(w * bf2f((unsigned short)vv[q]));
        *(short8*)&y1s[off] = o;
    }
}

// ------- gather layer 1: hb = bf16(relu(hbase - dinv[n] * sum(y1s[src]))) -------
// one wave per node; 8/4/1 unroll for deep MLP (rows are pre-scaled, no dinv load)
__global__ __launch_bounds__(256) void gather1_kernel(
    const int* __restrict__ row_beg, const int* __restrict__ row_end,
    const int* __restrict__ col, const float* __restrict__ dinv,
    const unsigned short* __restrict__ hbase, const unsigned short* __restrict__ y1s,
    short* __restrict__ hb) {
    int n = blockIdx.x * 4 + (threadIdx.x >> 6);
    if (n >= N_NODES) return;
    int lane = threadIdx.x & 63;
    int beg = row_beg[n], end = row_end[n];
    float acc = 0.f;
    int i = beg;
    for (; i + 8 <= end; i += 8) {
        int s0 = col[i], s1 = col[i + 1], s2 = col[i + 2], s3 = col[i + 3];
        int s4 = col[i + 4], s5 = col[i + 5], s6 = col[i + 6], s7 = col[i + 7];
        float v0 = bf2f(y1s[(size_t)s0 * H1 + lane]);
        float v1 = bf2f(y1s[(size_t)s1 * H1 + lane]);
        float v2 = bf2f(y1s[(size_t)s2 * H1 + lane]);
        float v3 = bf2f(y1s[(size_t)s3 * H1 + lane]);
        float v4 = bf2f(y1s[(size_t)s4 * H1 + lane]);
        float v5 = bf2f(y1s[(size_t)s5 * H1 + lane]);
        float v6 = bf2f(y1s[(size_t)s6 * H1 + lane]);
        float v7 = bf2f(y1s[(size_t)s7 * H1 + lane]);
        acc += ((v0 + v1) + (v2 + v3)) + ((v4 + v5) + (v6 + v7));
    }
    for (; i + 4 <= end; i += 4) {
        int s0 = col[i], s1 = col[i + 1], s2 = col[i + 2], s3 = col[i + 3];
        float v0 = bf2f(y1s[(size_t)s0 * H1 + lane]);
        float v1 = bf2f(y1s[(size_t)s1 * H1 + lane]);
        float v2 = bf2f(y1s[(size_t)s2 * H1 + lane]);
        float v3 = bf2f(y1s[(size_t)s3 * H1 + lane]);
        acc += (v0 + v1) + (v2 + v3);
    }
    for (; i < end; ++i)
        acc += bf2f(y1s[(size_t)col[i] * H1 + lane]);
    size_t idx = (size_t)n * H1 + lane;
    float hf = bf2f(hbase[idx]) - dinv[n] * acc;
    hb[idx] = f2bf(fmaxf(hf, 0.f));
}

// ---- layer-2 MFMA GEMM: out = relu(h)@W0_2 + b2 ; y2s = dinv[row] * (relu(h)@W1_2) ----
__global__ __launch_bounds__(256) void gemm2_mfma(
    const short* __restrict__ hb, const short* __restrict__ Bt2,
    const float* __restrict__ b2, const float* __restrict__ dinv,
    float* __restrict__ out, short* __restrict__ y2s) {
    int lane = threadIdx.x & 63;
    int wave = threadIdx.x >> 6;
    int rowbase = blockIdx.x * 128 + wave * 32;
    int lr = lane & 15;
    int lk = (lane >> 4) * 8;

    short8 a[2][2];
#pragma unroll
    for (int mr = 0; mr < 2; ++mr) {
        int row = rowbase + mr * 16 + lr;
        int rc = (row < N_NODES) ? row : (N_NODES - 1);
        const short* p = hb + (size_t)rc * H1 + lk;
        a[mr][0] = *(const short8*)(p);
        a[mr][1] = *(const short8*)(p + 32);
    }

    f32x4 acc[2][4] = {};
#pragma unroll
    for (int cf = 0; cf < 4; ++cf) {
        const short* bp = Bt2 + (size_t)(cf * 16 + lr) * H1 + lk;
#pragma unroll
        for (int ks = 0; ks < 2; ++ks) {
            short8 b = *(const short8*)(bp + ks * 32);
            acc[0][cf] = __builtin_amdgcn_mfma_f32_16x16x32_bf16(a[0][ks], b, acc[0][cf], 0, 0, 0);
            acc[1][cf] = __builtin_amdgcn_mfma_f32_16x16x32_bf16(a[1][ks], b, acc[1][cf], 0, 0, 0);
        }
    }

    int srow = (lane >> 4) * 4;
#pragma unroll
    for (int mr = 0; mr < 2; ++mr) {
#pragma unroll
        for (int cf = 0; cf < 4; ++cf) {
            int colc = cf * 16 + lr;
            float bias = (colc < H2) ? b2[colc] : 0.f;
#pragma unroll
            for (int r = 0; r < 4; ++r) {
                int row = rowbase + mr * 16 + srow + r;
                if (row < N_NODES) {
                    float v = acc[mr][cf][r];
                    if (colc < H2) out[(size_t)row * H2 + colc] = v + bias;
                    else           y2s[(size_t)row * H2 + (colc - H2)] = f2bf(dinv[row] * v);
                }
            }
        }
    }
}

// ------- gather layer 2: out[n] -= dinv[n] * sum(y2s[src]); 2 nodes/wave, 8/4/1 unroll -------
__global__ __launch_bounds__(256) void gather2_kernel(
    const int* __restrict__ row_beg, const int* __restrict__ row_end,
    const int* __restrict__ col, const float* __restrict__ dinv,
    const unsigned short* __restrict__ y2s, float* __restrict__ out) {
    int wave = (blockIdx.x * 256 + threadIdx.x) >> 6;
    int lane = threadIdx.x & 63;
    int n = wave * 2 + (lane >> 5);
    if (n >= N_NODES) return;
    int c32 = lane & 31;
    int beg = row_beg[n], end = row_end[n];
    float acc = 0.f;
    int i = beg;
    for (; i + 8 <= end; i += 8) {
        int s0 = col[i], s1 = col[i + 1], s2 = col[i + 2], s3 = col[i + 3];
        int s4 = col[i + 4], s5 = col[i + 5], s6 = col[i + 6], s7 = col[i + 7];
        float v0 = bf2f(y2s[(size_t)s0 * H2 + c32]);
        float v1 = bf2f(y2s[(size_t)s1 * H2 + c32]);
        float v2 = bf2f(y2s[(size_t)s2 * H2 + c32]);
        float v3 = bf2f(y2s[(size_t)s3 * H2 + c32]);
        float v4 = bf2f(y2s[(size_t)s4 * H2 + c32]);
        float v5 = bf2f(y2s[(size_t)s5 * H2 + c32]);
        float v6 = bf2f(y2s[(size_t)s6 * H2 + c32]);
        float v7 = bf2f(y2s[(size_t)s7 * H2 + c32]);
        acc += ((v0 + v1) + (v2 + v3)) + ((v4 + v5) + (v6 + v7));
    }
    for (; i + 4 <= end; i += 4) {
        int s0 = col[i], s1 = col[i + 1], s2 = col[i + 2], s3 = col[i + 3];
        float v0 = bf2f(y2s[(size_t)s0 * H2 + c32]);
        float v1 = bf2f(y2s[(size_t)s1 * H2 + c32]);
        float v2 = bf2f(y2s[(size_t)s2 * H2 + c32]);
        float v3 = bf2f(y2s[(size_t)s3 * H2 + c32]);
        acc += (v0 + v1) + (v2 + v3);
    }
    for (; i < end; ++i)
        acc += bf2f(y2s[(size_t)col[i] * H2 + c32]);
    size_t idx = (size_t)n * H2 + c32;
    out[idx] = out[idx] - dinv[n] * acc;
}

extern "C" void kernel_launch(void* const* d_in, const int* in_sizes, int n_in,
                              void* d_out, int out_size, void* d_ws, size_t ws_size,
                              hipStream_t stream) {
    const float* verts = (const float*)d_in[0];
    const int*   edges = (const int*)  d_in[1];
    const float* W0_1  = (const float*)d_in[2];
    const float* W1_1  = (const float*)d_in[3];
    const float* b1    = (const float*)d_in[4];
    const float* W0_2  = (const float*)d_in[5];
    const float* W1_2  = (const float*)d_in[6];
    const float* b2    = (const float*)d_in[7];
    float* out = (float*)d_out;

    char* ws = (char*)d_ws;
    auto align256 = [](size_t x) { return (x + 255) & ~(size_t)255; };
    size_t o = 0;
    auto alloc = [&](size_t bytes) { size_t r = o; o = align256(o + bytes); return r; };

    int*   bucket_next = (int*)  (ws + alloc((size_t)1024 * 4));
    int*   bins_dst    = (int*)  (ws + alloc((size_t)NBKT * CAP_D * 4));
    unsigned char* bins_src = (unsigned char*)(ws + alloc((size_t)NBKT * CAP_D));
    int*   col         = (int*)  (ws + alloc((size_t)NBKT * CAP_D * 4));
    int*   row_beg     = (int*)  (ws + alloc((size_t)N_NODES * 4));
    int*   row_end     = (int*)  (ws + alloc((size_t)N_NODES * 4));
    float* dinv        = (float*)(ws + alloc((size_t)N_NODES * 4));
    short* Bt1         = (short*)(ws + alloc((size_t)128 * IN_DIM * 2));
    short* Bt2         = (short*)(ws + alloc((size_t)64 * H1 * 2));
    short* hbase       = (short*)(ws + alloc((size_t)N_NODES * H1 * 2));
    short* y1b         = (short*)(ws + alloc((size_t)N_NODES * H1 * 2));
    short* y1s         = (short*)(ws + alloc((size_t)N_NODES * H1 * 2));
    short* hb          = (short*)(ws + alloc((size_t)N_NODES * H1 * 2));
    short* y2s         = (short*)(ws + alloc((size_t)N_NODES * H2 * 2));

    init_kernel  <<<1, 1024, 0, stream>>>(bucket_next);
    prep_w_kernel<<<(128 * IN_DIM + 64 * H1 + 255) / 256, 256, 0, stream>>>(W0_1, W1_1, W0_2, W1_2, Bt1, Bt2);

    k1_fused  <<<K1GRID, 256, 0, stream>>>(edges, bucket_next, bins_dst, bins_src,
                                           verts, Bt1, b1, hbase, y1b);
    csr_kernel<<<NBKT, 256, 0, stream>>>(bins_dst, bins_src, bucket_next, dinv,
                                         row_beg, row_end, col,
                                         (const unsigned short*)y1b, y1s);

    gather1_kernel<<<(N_NODES + 3) / 4, 256, 0, stream>>>(row_beg, row_end, col, dinv,
                                                          (const unsigned short*)hbase,
                                                          (const unsigned short*)y1s, hb);
    gemm2_mfma    <<<(N_NODES + 127) / 128, 256, 0, stream>>>(hb, Bt2, b2, dinv, out, y2s);
    gather2_kernel<<<(N_NODES + 7) / 8, 256, 0, stream>>>(row_beg, row_end, col, dinv,
                                                          (const unsigned short*)y2s, out);
}